// Round 2
// baseline (1186.542 us; speedup 1.0000x reference)
//
#include <hip/hip_runtime.h>

#define N_NODES 100000
#define N_EDGES 1600000
#define C_H     128
#define C_OUT   40
#define K_FC    384
#define BN_EPS  1e-5f

// ---------------------------------------------------------------- utilities
__global__ void zero_i32(int* p, int n) {
    int i = blockIdx.x * blockDim.x + threadIdx.x;
    if (i < n) p[i] = 0;
}

__global__ void count_deg(const int* __restrict__ erow, int* __restrict__ deg) {
    int e = blockIdx.x * blockDim.x + threadIdx.x;
    if (e < N_EDGES) atomicAdd(&deg[erow[e]], 1);
}

__global__ void compute_dinv(const int* __restrict__ deg, float* __restrict__ dinv) {
    int i = blockIdx.x * blockDim.x + threadIdx.x;
    if (i < N_NODES) dinv[i] = rsqrtf((float)deg[i] + 1.0f);
}

// Block-level exclusive scan of deg -> rowptr (partial, needs block offsets).
__global__ __launch_bounds__(1024) void scan_block(const int* __restrict__ deg,
                                                   int* __restrict__ excl,
                                                   int* __restrict__ bsums) {
    __shared__ int sm[1024];
    int i = blockIdx.x * 1024 + threadIdx.x;
    int v = (i < N_NODES) ? deg[i] : 0;
    sm[threadIdx.x] = v;
    __syncthreads();
    for (int off = 1; off < 1024; off <<= 1) {
        int add = (threadIdx.x >= off) ? sm[threadIdx.x - off] : 0;
        __syncthreads();
        sm[threadIdx.x] += add;
        __syncthreads();
    }
    if (i < N_NODES) excl[i] = sm[threadIdx.x] - v;   // exclusive within block
    if (threadIdx.x == 1023) bsums[blockIdx.x] = sm[1023];
}

__global__ void scan_sums(int* __restrict__ bs, int nb) {
    __shared__ int sm[128];
    int tid = threadIdx.x;
    if (tid < nb) sm[tid] = bs[tid];
    __syncthreads();
    if (tid == 0) {
        int acc = 0;
        for (int i = 0; i < nb; ++i) { int t = sm[i]; sm[i] = acc; acc += t; }
    }
    __syncthreads();
    if (tid < nb) bs[tid] = sm[tid];
}

__global__ __launch_bounds__(1024) void add_offsets(int* __restrict__ rowptr,
                                                    const int* __restrict__ bsums,
                                                    int* __restrict__ fill) {
    int i = blockIdx.x * 1024 + threadIdx.x;
    if (i < N_NODES) {
        int v = rowptr[i] + bsums[blockIdx.x];
        rowptr[i] = v;
        fill[i] = v;
    }
    if (blockIdx.x == 0 && threadIdx.x == 0) rowptr[N_NODES] = N_EDGES;
}

__global__ void fill_csr(const int* __restrict__ erow, const int* __restrict__ ecol,
                         int* __restrict__ fill, int* __restrict__ cols) {
    int e = blockIdx.x * blockDim.x + threadIdx.x;
    if (e < N_EDGES) {
        int r = erow[e];
        int p = atomicAdd(&fill[r], 1);
        cols[p] = ecol[e];
    }
}

// Fold bias + BN into per-channel scale s and offset t:
// relu(bn(agg + b)) = relu(agg*s + t), s = gamma*rsqrt(var+eps), t = (b-mean)*s + beta
__global__ void bn_coef(const float* b1, const float* g1, const float* be1,
                        const float* m1, const float* v1,
                        const float* b2, const float* g2, const float* be2,
                        const float* m2, const float* v2,
                        float* s1, float* t1, float* s2, float* t2) {
    int f = threadIdx.x;  // 128
    float sa = g1[f] * rsqrtf(v1[f] + BN_EPS);
    s1[f] = sa;
    t1[f] = (b1[f] - m1[f]) * sa + be1[f];
    float sb = g2[f] * rsqrtf(v2[f] + BN_EPS);
    s2[f] = sb;
    t2[f] = (b2[f] - m2[f]) * sb + be2[f];
}

// ------------------------------------------------- dense GEMM: Y = X @ W (128x128)
// NOTE: macro params must NOT be named x/y/z/w — member access collides.
#define FMA4(A, S, V) \
    A.x = fmaf(S, V.x, A.x); A.y = fmaf(S, V.y, A.y); \
    A.z = fmaf(S, V.z, A.z); A.w = fmaf(S, V.w, A.w);

__global__ __launch_bounds__(256) void gemm_128x128(const float* __restrict__ X,
                                                    const float* __restrict__ W,
                                                    float* __restrict__ Y) {
    __shared__ float Wl[128 * 128];  // 64 KB
    for (int i = threadIdx.x; i < 128 * 128 / 4; i += 256)
        ((float4*)Wl)[i] = ((const float4*)W)[i];
    __syncthreads();

    const int c4 = (threadIdx.x & 31) << 2;   // 4 output cols
    const int rg = threadIdx.x >> 5;          // 0..7
    const int r0 = blockIdx.x * 16 + rg * 2;  // 2 rows per thread

    const float4* xa4 = (const float4*)(X + (size_t)r0 * 128);
    const float4* xb4 = (const float4*)(X + (size_t)(r0 + 1) * 128);
    float4 a0 = {0, 0, 0, 0}, a1 = {0, 0, 0, 0};

    #pragma unroll 4
    for (int k4 = 0; k4 < 32; ++k4) {
        float4 xa = xa4[k4];
        float4 xb = xb4[k4];
        const float* wr = Wl + k4 * 4 * 128 + c4;
        float4 w0 = *(const float4*)(wr);
        float4 w1 = *(const float4*)(wr + 128);
        float4 w2 = *(const float4*)(wr + 256);
        float4 w3 = *(const float4*)(wr + 384);
        FMA4(a0, xa.x, w0) FMA4(a0, xa.y, w1) FMA4(a0, xa.z, w2) FMA4(a0, xa.w, w3)
        FMA4(a1, xb.x, w0) FMA4(a1, xb.y, w1) FMA4(a1, xb.z, w2) FMA4(a1, xb.w, w3)
    }
    *(float4*)(Y + (size_t)r0 * 128 + c4) = a0;
    *(float4*)(Y + (size_t)(r0 + 1) * 128 + c4) = a1;
}

// ------------------------- fused SpMM + self-loop + bias/BN + ReLU (one block/row)
__global__ __launch_bounds__(128) void spmm_bn_relu(
    const float* __restrict__ H, const int* __restrict__ cols,
    const int* __restrict__ rowptr, const float* __restrict__ dinv,
    const float* __restrict__ s, const float* __restrict__ t,
    float* __restrict__ Y) {
    const int r = blockIdx.x;
    const int f = threadIdx.x;
    const float di = dinv[r];
    float acc = di * H[(size_t)r * C_H + f];  // self-loop: di^2 * h[r] after *di below
    const int e0 = rowptr[r], e1 = rowptr[r + 1];
    for (int j = e0; j < e1; ++j) {
        const int c = cols[j];
        acc = fmaf(dinv[c], H[(size_t)c * C_H + f], acc);
    }
    acc *= di;
    float v = fmaf(acc, s[f], t[f]);
    Y[(size_t)r * C_H + f] = fmaxf(v, 0.0f);
}

// ------------------------------ final FC: out = [x0|x1|x2] @ fcW + fcb (384 -> 40)
__global__ __launch_bounds__(256) void final_gemm(
    const float* __restrict__ X0, const float* __restrict__ X1,
    const float* __restrict__ X2, const float* __restrict__ fcW,
    const float* __restrict__ fcb, float* __restrict__ out) {
    __shared__ float Wl[K_FC * C_OUT];  // 61440 B
    for (int i = threadIdx.x; i < K_FC * C_OUT; i += 256) Wl[i] = fcW[i];
    __syncthreads();

    const int c = threadIdx.x & 63;
    const int cw = c < C_OUT ? c : C_OUT - 1;   // clamp to stay in-bounds
    const int rg = threadIdx.x >> 6;            // wave id 0..3
    const int rbase = blockIdx.x * 16 + rg;     // rows rbase + {0,4,8,12}

    float acc0 = 0, acc1 = 0, acc2 = 0, acc3 = 0;
    const float* segs[3] = {X0, X1, X2};
    for (int s3 = 0; s3 < 3; ++s3) {
        const float* xs = segs[s3];
        const float4* p0 = (const float4*)(xs + (size_t)(rbase) * 128);
        const float4* p1 = (const float4*)(xs + (size_t)(rbase + 4) * 128);
        const float4* p2 = (const float4*)(xs + (size_t)(rbase + 8) * 128);
        const float4* p3 = (const float4*)(xs + (size_t)(rbase + 12) * 128);
        const float* wbase = Wl + s3 * 128 * C_OUT + cw;
        #pragma unroll 4
        for (int k4 = 0; k4 < 32; ++k4) {
            float4 v0 = p0[k4], v1 = p1[k4], v2 = p2[k4], v3 = p3[k4];
            const float* wr = wbase + k4 * 4 * C_OUT;
            float w0 = wr[0], w1 = wr[C_OUT], w2 = wr[2 * C_OUT], w3 = wr[3 * C_OUT];
            acc0 = fmaf(v0.x, w0, acc0); acc0 = fmaf(v0.y, w1, acc0);
            acc0 = fmaf(v0.z, w2, acc0); acc0 = fmaf(v0.w, w3, acc0);
            acc1 = fmaf(v1.x, w0, acc1); acc1 = fmaf(v1.y, w1, acc1);
            acc1 = fmaf(v1.z, w2, acc1); acc1 = fmaf(v1.w, w3, acc1);
            acc2 = fmaf(v2.x, w0, acc2); acc2 = fmaf(v2.y, w1, acc2);
            acc2 = fmaf(v2.z, w2, acc2); acc2 = fmaf(v2.w, w3, acc2);
            acc3 = fmaf(v3.x, w0, acc3); acc3 = fmaf(v3.y, w1, acc3);
            acc3 = fmaf(v3.z, w2, acc3); acc3 = fmaf(v3.w, w3, acc3);
        }
    }
    if (c < C_OUT) {
        float bb = fcb[c];
        out[(size_t)(rbase) * C_OUT + c] = acc0 + bb;
        out[(size_t)(rbase + 4) * C_OUT + c] = acc1 + bb;
        out[(size_t)(rbase + 8) * C_OUT + c] = acc2 + bb;
        out[(size_t)(rbase + 12) * C_OUT + c] = acc3 + bb;
    }
}

// ---------------------------------------------------------------------------
extern "C" void kernel_launch(void* const* d_in, const int* in_sizes, int n_in,
                              void* d_out, int out_size, void* d_ws, size_t ws_size,
                              hipStream_t stream) {
    const float* x   = (const float*)d_in[0];
    const int*   ei  = (const int*)d_in[1];
    const int* e_row = ei;             // edge_index[0]
    const int* e_col = ei + N_EDGES;   // edge_index[1]
    const float* W1  = (const float*)d_in[2];
    const float* b1  = (const float*)d_in[3];
    const float* W2  = (const float*)d_in[4];
    const float* b2  = (const float*)d_in[5];
    const float* g1  = (const float*)d_in[6];
    const float* be1 = (const float*)d_in[7];
    const float* m1  = (const float*)d_in[8];
    const float* v1  = (const float*)d_in[9];
    const float* g2  = (const float*)d_in[10];
    const float* be2 = (const float*)d_in[11];
    const float* m2  = (const float*)d_in[12];
    const float* v2  = (const float*)d_in[13];
    const float* fcW = (const float*)d_in[14];
    const float* fcb = (const float*)d_in[15];
    float* out = (float*)d_out;

    char* ws = (char*)d_ws;
    size_t off = 0;
    auto alloc = [&](size_t b) {
        char* p = ws + off;
        off += (b + 255) & ~(size_t)255;
        return p;
    };
    float* h      = (float*)alloc((size_t)N_NODES * C_H * 4);
    float* x1     = (float*)alloc((size_t)N_NODES * C_H * 4);
    float* x2     = (float*)alloc((size_t)N_NODES * C_H * 4);
    int*   deg    = (int*)alloc(N_NODES * 4);
    float* dinv   = (float*)alloc(N_NODES * 4);
    int*   rowptr = (int*)alloc((N_NODES + 1) * 4);
    int*   fillc  = (int*)alloc(N_NODES * 4);
    int*   cols   = (int*)alloc((size_t)N_EDGES * 4);
    int*   bsums  = (int*)alloc(128 * 4);
    float* coef   = (float*)alloc(512 * 4);
    float* s1 = coef, *t1 = coef + 128, *s2 = coef + 256, *t2 = coef + 384;

    const int nb_scan = (N_NODES + 1023) / 1024;  // 98

    zero_i32<<<(N_NODES + 255) / 256, 256, 0, stream>>>(deg, N_NODES);
    count_deg<<<(N_EDGES + 255) / 256, 256, 0, stream>>>(e_row, deg);
    compute_dinv<<<(N_NODES + 255) / 256, 256, 0, stream>>>(deg, dinv);
    scan_block<<<nb_scan, 1024, 0, stream>>>(deg, rowptr, bsums);
    scan_sums<<<1, 128, 0, stream>>>(bsums, nb_scan);
    add_offsets<<<nb_scan, 1024, 0, stream>>>(rowptr, bsums, fillc);
    fill_csr<<<(N_EDGES + 255) / 256, 256, 0, stream>>>(e_row, e_col, fillc, cols);
    bn_coef<<<1, 128, 0, stream>>>(b1, g1, be1, m1, v1, b2, g2, be2, m2, v2,
                                   s1, t1, s2, t2);

    gemm_128x128<<<N_NODES / 16, 256, 0, stream>>>(x, W1, h);
    spmm_bn_relu<<<N_NODES, 128, 0, stream>>>(h, cols, rowptr, dinv, s1, t1, x1);
    gemm_128x128<<<N_NODES / 16, 256, 0, stream>>>(x1, W2, h);  // reuse h
    spmm_bn_relu<<<N_NODES, 128, 0, stream>>>(h, cols, rowptr, dinv, s2, t2, x2);
    final_gemm<<<N_NODES / 16, 256, 0, stream>>>(x, x1, x2, fcW, fcb, out);
}

// Round 3
// 900.224 us; speedup vs baseline: 1.3181x; 1.3181x over previous
//
#include <hip/hip_runtime.h>

#define N_NODES 100000
#define N_EDGES 1600000
#define C_H     128
#define C_OUT   40
#define K_FC    384
#define BN_EPS  1e-5f

// ---------------------------------------------------------------- utilities
__global__ void zero_i32(int* p, int n) {
    int i = blockIdx.x * blockDim.x + threadIdx.x;
    if (i < n) p[i] = 0;
}

__global__ void count_deg(const int* __restrict__ erow, int* __restrict__ deg) {
    int e = blockIdx.x * blockDim.x + threadIdx.x;
    if (e < N_EDGES) atomicAdd(&deg[erow[e]], 1);
}

__global__ void compute_dinv(const int* __restrict__ deg, float* __restrict__ dinv) {
    int i = blockIdx.x * blockDim.x + threadIdx.x;
    if (i < N_NODES) dinv[i] = rsqrtf((float)deg[i] + 1.0f);
}

__global__ __launch_bounds__(1024) void scan_block(const int* __restrict__ deg,
                                                   int* __restrict__ excl,
                                                   int* __restrict__ bsums) {
    __shared__ int sm[1024];
    int i = blockIdx.x * 1024 + threadIdx.x;
    int v = (i < N_NODES) ? deg[i] : 0;
    sm[threadIdx.x] = v;
    __syncthreads();
    for (int off = 1; off < 1024; off <<= 1) {
        int add = (threadIdx.x >= off) ? sm[threadIdx.x - off] : 0;
        __syncthreads();
        sm[threadIdx.x] += add;
        __syncthreads();
    }
    if (i < N_NODES) excl[i] = sm[threadIdx.x] - v;
    if (threadIdx.x == 1023) bsums[blockIdx.x] = sm[1023];
}

__global__ void scan_sums(int* __restrict__ bs, int nb) {
    __shared__ int sm[128];
    int tid = threadIdx.x;
    if (tid < nb) sm[tid] = bs[tid];
    __syncthreads();
    if (tid == 0) {
        int acc = 0;
        for (int i = 0; i < nb; ++i) { int t = sm[i]; sm[i] = acc; acc += t; }
    }
    __syncthreads();
    if (tid < nb) bs[tid] = sm[tid];
}

__global__ __launch_bounds__(1024) void add_offsets(int* __restrict__ rowptr,
                                                    const int* __restrict__ bsums,
                                                    int* __restrict__ fill) {
    int i = blockIdx.x * 1024 + threadIdx.x;
    if (i < N_NODES) {
        int v = rowptr[i] + bsums[blockIdx.x];
        rowptr[i] = v;
        fill[i] = v;
    }
    if (blockIdx.x == 0 && threadIdx.x == 0) rowptr[N_NODES] = N_EDGES;
}

__global__ void fill_csr(const int* __restrict__ erow, const int* __restrict__ ecol,
                         int* __restrict__ fill, int* __restrict__ cols) {
    int e = blockIdx.x * blockDim.x + threadIdx.x;
    if (e < N_EDGES) {
        int r = erow[e];
        int p = atomicAdd(&fill[r], 1);
        cols[p] = ecol[e];
    }
}

// relu(bn(agg + b)) = relu(agg*s + t)
__global__ void bn_coef(const float* b1, const float* g1, const float* be1,
                        const float* m1, const float* v1,
                        const float* b2, const float* g2, const float* be2,
                        const float* m2, const float* v2,
                        float* s1, float* t1, float* s2, float* t2) {
    int f = threadIdx.x;
    float sa = g1[f] * rsqrtf(v1[f] + BN_EPS);
    s1[f] = sa;
    t1[f] = (b1[f] - m1[f]) * sa + be1[f];
    float sb = g2[f] * rsqrtf(v2[f] + BN_EPS);
    s2[f] = sb;
    t2[f] = (b2[f] - m2[f]) * sb + be2[f];
}

#define FMA4(A, S, V) \
    A.x = fmaf(S, V.x, A.x); A.y = fmaf(S, V.y, A.y); \
    A.z = fmaf(S, V.z, A.z); A.w = fmaf(S, V.w, A.w);

// -------------------- GEMM + dinv prescale: Hs = diag(dinv) * (X @ W)
// 32 rows/block, 4 rows/thread, W staged in 32KB k-halves, X tile via LDS.
// LDS = 32768 + 8704 = 41472 B -> 3 blocks/CU.
__global__ __launch_bounds__(256) void gemm_scaled(const float* __restrict__ X,
                                                   const float* __restrict__ W,
                                                   const float* __restrict__ dinv,
                                                   float* __restrict__ Hs) {
    __shared__ float wl[64 * 128];   // k-half of W  (32 KB)
    __shared__ float xl[32 * 68];    // 32 rows x 64 cols, stride 68 (8704 B)

    const int tid = threadIdx.x;
    const int rg = tid >> 5;             // 0..7
    const int c4 = (tid & 31) << 2;      // output cols
    const int rb = blockIdx.x * 32;
    const int r0 = rb + rg * 4;          // 4 rows per thread

    float4 acc0 = {0,0,0,0}, acc1 = {0,0,0,0}, acc2 = {0,0,0,0}, acc3 = {0,0,0,0};

    for (int half = 0; half < 2; ++half) {
        const int k0 = half * 64;
        __syncthreads();
        // stage W[k0..k0+63][0..127] : 2048 float4, 8 per thread, coalesced
        {
            const float4* W4 = (const float4*)(W + (size_t)k0 * 128);
            float4* wl4 = (float4*)wl;
            #pragma unroll
            for (int i = 0; i < 8; ++i) wl4[tid + i * 256] = W4[tid + i * 256];
        }
        // stage X[rb..rb+31][k0..k0+63] : 512 float4, 2 per thread
        #pragma unroll
        for (int i = 0; i < 2; ++i) {
            int f = tid + i * 256;           // 0..511
            int row = f >> 4, cc = f & 15;
            float4 v = *(const float4*)(X + (size_t)(rb + row) * 128 + k0 + cc * 4);
            *(float4*)&xl[row * 68 + cc * 4] = v;
        }
        __syncthreads();

        for (int k4 = 0; k4 < 16; ++k4) {
            const float* wr = wl + k4 * 4 * 128 + c4;
            float4 w0 = *(const float4*)(wr);
            float4 w1 = *(const float4*)(wr + 128);
            float4 w2 = *(const float4*)(wr + 256);
            float4 w3 = *(const float4*)(wr + 384);
            float4 xv0 = *(const float4*)&xl[(rg * 4 + 0) * 68 + k4 * 4];
            float4 xv1 = *(const float4*)&xl[(rg * 4 + 1) * 68 + k4 * 4];
            float4 xv2 = *(const float4*)&xl[(rg * 4 + 2) * 68 + k4 * 4];
            float4 xv3 = *(const float4*)&xl[(rg * 4 + 3) * 68 + k4 * 4];
            FMA4(acc0, xv0.x, w0) FMA4(acc0, xv0.y, w1) FMA4(acc0, xv0.z, w2) FMA4(acc0, xv0.w, w3)
            FMA4(acc1, xv1.x, w0) FMA4(acc1, xv1.y, w1) FMA4(acc1, xv1.z, w2) FMA4(acc1, xv1.w, w3)
            FMA4(acc2, xv2.x, w0) FMA4(acc2, xv2.y, w1) FMA4(acc2, xv2.z, w2) FMA4(acc2, xv2.w, w3)
            FMA4(acc3, xv3.x, w0) FMA4(acc3, xv3.y, w1) FMA4(acc3, xv3.z, w2) FMA4(acc3, xv3.w, w3)
        }
    }
    float d0 = dinv[r0], d1 = dinv[r0 + 1], d2 = dinv[r0 + 2], d3 = dinv[r0 + 3];
    float4 o;
    o.x = acc0.x * d0; o.y = acc0.y * d0; o.z = acc0.z * d0; o.w = acc0.w * d0;
    *(float4*)(Hs + (size_t)(r0 + 0) * 128 + c4) = o;
    o.x = acc1.x * d1; o.y = acc1.y * d1; o.z = acc1.z * d1; o.w = acc1.w * d1;
    *(float4*)(Hs + (size_t)(r0 + 1) * 128 + c4) = o;
    o.x = acc2.x * d2; o.y = acc2.y * d2; o.z = acc2.z * d2; o.w = acc2.w * d2;
    *(float4*)(Hs + (size_t)(r0 + 2) * 128 + c4) = o;
    o.x = acc3.x * d3; o.y = acc3.y * d3; o.z = acc3.z * d3; o.w = acc3.w * d3;
    *(float4*)(Hs + (size_t)(r0 + 3) * 128 + c4) = o;
}

// -------------------- SpMM on prescaled Hs: one wave per row, float2/lane.
// out[r] = relu( s * ( dinv[r]*(sum_edges Hs[c] + Hs[r]) ) + t )
__global__ __launch_bounds__(256) void spmm_bn_relu2(
    const float* __restrict__ Hs, const int* __restrict__ cols,
    const int* __restrict__ rowptr, const float* __restrict__ dinv,
    const float* __restrict__ s, const float* __restrict__ t,
    float* __restrict__ Y) {
    const int lane = threadIdx.x & 63;
    const int r = blockIdx.x * 4 + (threadIdx.x >> 6);
    const float2* H2 = (const float2*)Hs;

    float2 acc = H2[(size_t)r * 64 + lane];   // self term (prescaled)
    const float di = dinv[r];
    const int e1 = rowptr[r + 1];
    int j = rowptr[r];
    for (; j + 1 < e1; j += 2) {
        int c0 = cols[j], c1 = cols[j + 1];
        float2 a = H2[(size_t)c0 * 64 + lane];
        float2 b = H2[(size_t)c1 * 64 + lane];
        acc.x += a.x + b.x;
        acc.y += a.y + b.y;
    }
    if (j < e1) {
        int c0 = cols[j];
        float2 a = H2[(size_t)c0 * 64 + lane];
        acc.x += a.x; acc.y += a.y;
    }
    float2 sf = ((const float2*)s)[lane];
    float2 tf = ((const float2*)t)[lane];
    float2 o;
    o.x = fmaxf(fmaf(acc.x * di, sf.x, tf.x), 0.0f);
    o.y = fmaxf(fmaf(acc.y * di, sf.y, tf.y), 0.0f);
    ((float2*)Y)[(size_t)r * 64 + lane] = o;
}

// -------------------- final FC: out = [x0|x1|x2] @ fcW + fcb  (384 -> 40)
// 128 threads, 512 rows/block, 4 rows/thread (acc[4][40] in VGPRs),
// X chunk (16 k) + W^T chunk staged in LDS. LDS = 40960+2560 = 43520 B.
__global__ __launch_bounds__(128, 2) void final_gemm2(
    const float* __restrict__ X0, const float* __restrict__ X1,
    const float* __restrict__ X2, const float* __restrict__ fcW,
    const float* __restrict__ fcb, float* __restrict__ out) {
    __shared__ float xs[512 * 20];   // 512 rows x 16 k, stride 20 (b128-aligned, conflict-ok)
    __shared__ float wt[40 * 16];    // wt[c][kk]

    const int t = threadIdx.x;
    const int rbase = blockIdx.x * 512;

    float acc[4][40];
    #pragma unroll
    for (int rr = 0; rr < 4; ++rr)
        #pragma unroll
        for (int c = 0; c < 40; ++c) acc[rr][c] = 0.0f;

    const float* segs[3] = {X0, X1, X2};

    for (int ch = 0; ch < 24; ++ch) {
        const int k0 = ch * 16;
        const float* xseg = segs[k0 >> 7];
        const int koff = k0 & 127;
        __syncthreads();
        // stage X: 512 rows x 16 cols = 2048 float4, 16 per thread
        #pragma unroll
        for (int i = 0; i < 16; ++i) {
            int f = t + i * 128;            // 0..2047
            int row = f >> 2, cc = f & 3;
            int r = rbase + row;
            float4 v = {0, 0, 0, 0};
            if (r < N_NODES)
                v = *(const float4*)(xseg + (size_t)r * 128 + koff + cc * 4);
            *(float4*)&xs[row * 20 + cc * 4] = v;
        }
        // stage W^T chunk: 640 floats, 5 per thread
        #pragma unroll
        for (int i = 0; i < 5; ++i) {
            int idx = t + i * 128;          // 0..639
            int c = idx % 40, kk = idx / 40;
            wt[c * 16 + kk] = fcW[(size_t)(k0 + kk) * 40 + c];
        }
        __syncthreads();

        for (int kk4 = 0; kk4 < 4; ++kk4) {
            float4 xv[4];
            #pragma unroll
            for (int rr = 0; rr < 4; ++rr)
                xv[rr] = *(const float4*)&xs[(t + rr * 128) * 20 + kk4 * 4];
            #pragma unroll
            for (int c = 0; c < 40; ++c) {
                float4 wv = *(const float4*)&wt[c * 16 + kk4 * 4];
                #pragma unroll
                for (int rr = 0; rr < 4; ++rr) {
                    acc[rr][c] = fmaf(xv[rr].x, wv.x, acc[rr][c]);
                    acc[rr][c] = fmaf(xv[rr].y, wv.y, acc[rr][c]);
                    acc[rr][c] = fmaf(xv[rr].z, wv.z, acc[rr][c]);
                    acc[rr][c] = fmaf(xv[rr].w, wv.w, acc[rr][c]);
                }
            }
        }
    }

    #pragma unroll
    for (int rr = 0; rr < 4; ++rr) {
        int r = rbase + t + rr * 128;
        if (r < N_NODES) {
            #pragma unroll
            for (int c4 = 0; c4 < 10; ++c4) {
                float4 o;
                o.x = acc[rr][c4 * 4 + 0] + fcb[c4 * 4 + 0];
                o.y = acc[rr][c4 * 4 + 1] + fcb[c4 * 4 + 1];
                o.z = acc[rr][c4 * 4 + 2] + fcb[c4 * 4 + 2];
                o.w = acc[rr][c4 * 4 + 3] + fcb[c4 * 4 + 3];
                *(float4*)(out + (size_t)r * 40 + c4 * 4) = o;
            }
        }
    }
}

// ---------------------------------------------------------------------------
extern "C" void kernel_launch(void* const* d_in, const int* in_sizes, int n_in,
                              void* d_out, int out_size, void* d_ws, size_t ws_size,
                              hipStream_t stream) {
    const float* x   = (const float*)d_in[0];
    const int*   ei  = (const int*)d_in[1];
    const int* e_row = ei;
    const int* e_col = ei + N_EDGES;
    const float* W1  = (const float*)d_in[2];
    const float* b1  = (const float*)d_in[3];
    const float* W2  = (const float*)d_in[4];
    const float* b2  = (const float*)d_in[5];
    const float* g1  = (const float*)d_in[6];
    const float* be1 = (const float*)d_in[7];
    const float* m1  = (const float*)d_in[8];
    const float* v1  = (const float*)d_in[9];
    const float* g2  = (const float*)d_in[10];
    const float* be2 = (const float*)d_in[11];
    const float* m2  = (const float*)d_in[12];
    const float* v2  = (const float*)d_in[13];
    const float* fcW = (const float*)d_in[14];
    const float* fcb = (const float*)d_in[15];
    float* out = (float*)d_out;

    char* ws = (char*)d_ws;
    size_t off = 0;
    auto alloc = [&](size_t b) {
        char* p = ws + off;
        off += (b + 255) & ~(size_t)255;
        return p;
    };
    float* h      = (float*)alloc((size_t)N_NODES * C_H * 4);
    float* x1     = (float*)alloc((size_t)N_NODES * C_H * 4);
    float* x2     = (float*)alloc((size_t)N_NODES * C_H * 4);
    int*   deg    = (int*)alloc(N_NODES * 4);
    float* dinv   = (float*)alloc(N_NODES * 4);
    int*   rowptr = (int*)alloc((N_NODES + 1) * 4);
    int*   fillc  = (int*)alloc(N_NODES * 4);
    int*   cols   = (int*)alloc((size_t)N_EDGES * 4);
    int*   bsums  = (int*)alloc(128 * 4);
    float* coef   = (float*)alloc(512 * 4);
    float* s1 = coef, *t1 = coef + 128, *s2 = coef + 256, *t2 = coef + 384;

    const int nb_scan = (N_NODES + 1023) / 1024;

    zero_i32<<<(N_NODES + 255) / 256, 256, 0, stream>>>(deg, N_NODES);
    count_deg<<<(N_EDGES + 255) / 256, 256, 0, stream>>>(e_row, deg);
    compute_dinv<<<(N_NODES + 255) / 256, 256, 0, stream>>>(deg, dinv);
    scan_block<<<nb_scan, 1024, 0, stream>>>(deg, rowptr, bsums);
    scan_sums<<<1, 128, 0, stream>>>(bsums, nb_scan);
    add_offsets<<<nb_scan, 1024, 0, stream>>>(rowptr, bsums, fillc);
    fill_csr<<<(N_EDGES + 255) / 256, 256, 0, stream>>>(e_row, e_col, fillc, cols);
    bn_coef<<<1, 128, 0, stream>>>(b1, g1, be1, m1, v1, b2, g2, be2, m2, v2,
                                   s1, t1, s2, t2);

    gemm_scaled<<<N_NODES / 32, 256, 0, stream>>>(x, W1, dinv, h);
    spmm_bn_relu2<<<N_NODES / 4, 256, 0, stream>>>(h, cols, rowptr, dinv, s1, t1, x1);
    gemm_scaled<<<N_NODES / 32, 256, 0, stream>>>(x1, W2, dinv, h);
    spmm_bn_relu2<<<N_NODES / 4, 256, 0, stream>>>(h, cols, rowptr, dinv, s2, t2, x2);
    final_gemm2<<<(N_NODES + 511) / 512, 128, 0, stream>>>(x, x1, x2, fcW, fcb, out);
}

// Round 4
// 687.196 us; speedup vs baseline: 1.7266x; 1.3100x over previous
//
#include <hip/hip_runtime.h>

#define N_NODES 100000
#define N_EDGES 1600000
#define C_H     128
#define C_OUT   40
#define K_FC    384
#define BN_EPS  1e-5f

typedef unsigned int uint;

// ---------------------------------------------------------------- utilities
__global__ void zero_i32(int* p, int n) {
    int i = blockIdx.x * blockDim.x + threadIdx.x;
    if (i < n) p[i] = 0;
}

__global__ void count_deg(const int* __restrict__ erow, int* __restrict__ deg) {
    int e = blockIdx.x * blockDim.x + threadIdx.x;
    if (e < N_EDGES) atomicAdd(&deg[erow[e]], 1);
}

__global__ void compute_dinv(const int* __restrict__ deg, float* __restrict__ dinv) {
    int i = blockIdx.x * blockDim.x + threadIdx.x;
    if (i < N_NODES) dinv[i] = rsqrtf((float)deg[i] + 1.0f);
}

__global__ __launch_bounds__(1024) void scan_block(const int* __restrict__ deg,
                                                   int* __restrict__ excl,
                                                   int* __restrict__ bsums) {
    __shared__ int sm[1024];
    int i = blockIdx.x * 1024 + threadIdx.x;
    int v = (i < N_NODES) ? deg[i] : 0;
    sm[threadIdx.x] = v;
    __syncthreads();
    for (int off = 1; off < 1024; off <<= 1) {
        int add = (threadIdx.x >= off) ? sm[threadIdx.x - off] : 0;
        __syncthreads();
        sm[threadIdx.x] += add;
        __syncthreads();
    }
    if (i < N_NODES) excl[i] = sm[threadIdx.x] - v;
    if (threadIdx.x == 1023) bsums[blockIdx.x] = sm[1023];
}

__global__ void scan_sums(int* __restrict__ bs, int nb) {
    __shared__ int sm[128];
    int tid = threadIdx.x;
    if (tid < nb) sm[tid] = bs[tid];
    __syncthreads();
    if (tid == 0) {
        int acc = 0;
        for (int i = 0; i < nb; ++i) { int t = sm[i]; sm[i] = acc; acc += t; }
    }
    __syncthreads();
    if (tid < nb) bs[tid] = sm[tid];
}

__global__ __launch_bounds__(1024) void add_offsets(int* __restrict__ rowptr,
                                                    const int* __restrict__ bsums,
                                                    int* __restrict__ fill) {
    int i = blockIdx.x * 1024 + threadIdx.x;
    if (i < N_NODES) {
        int v = rowptr[i] + bsums[blockIdx.x];
        rowptr[i] = v;
        fill[i] = v;
    }
    if (blockIdx.x == 0 && threadIdx.x == 0) rowptr[N_NODES] = N_EDGES;
}

__global__ void fill_csr(const int* __restrict__ erow, const int* __restrict__ ecol,
                         int* __restrict__ fill, int* __restrict__ cols) {
    int e = blockIdx.x * blockDim.x + threadIdx.x;
    if (e < N_EDGES) {
        int r = erow[e];
        int p = atomicAdd(&fill[r], 1);
        cols[p] = ecol[e];
    }
}

// relu(bn(agg + b)) = relu(agg*s + t)
__global__ void bn_coef(const float* b1, const float* g1, const float* be1,
                        const float* m1, const float* v1,
                        const float* b2, const float* g2, const float* be2,
                        const float* m2, const float* v2,
                        float* s1, float* t1, float* s2, float* t2) {
    int f = threadIdx.x;
    float sa = g1[f] * rsqrtf(v1[f] + BN_EPS);
    s1[f] = sa;
    t1[f] = (b1[f] - m1[f]) * sa + be1[f];
    float sb = g2[f] * rsqrtf(v2[f] + BN_EPS);
    s2[f] = sb;
    t2[f] = (b2[f] - m2[f]) * sb + be2[f];
}

#define FMA4(A, S, V) \
    A.x = fmaf(S, V.x, A.x); A.y = fmaf(S, V.y, A.y); \
    A.z = fmaf(S, V.z, A.z); A.w = fmaf(S, V.w, A.w);

__device__ inline uint pack_bf16x2(float a, float b) {
    uint ua = __builtin_bit_cast(uint, a);
    uint ub = __builtin_bit_cast(uint, b);
    ua += 0x7fffu + ((ua >> 16) & 1u);   // RNE
    ub += 0x7fffu + ((ub >> 16) & 1u);
    return (ua >> 16) | (ub & 0xffff0000u);
}

// -------------------- GEMM + dinv prescale: Hs(bf16) = diag(dinv) * (X @ W)
// 32 rows/block, 4 rows/thread, W staged in 32KB k-halves, X tile via LDS.
__global__ __launch_bounds__(256) void gemm_scaled(const float* __restrict__ X,
                                                   const float* __restrict__ W,
                                                   const float* __restrict__ dinv,
                                                   uint* __restrict__ Hs) {
    __shared__ float wl[64 * 128];   // k-half of W  (32 KB)
    __shared__ float xl[32 * 68];    // 32 rows x 64 cols, stride 68

    const int tid = threadIdx.x;
    const int rg = tid >> 5;
    const int c4 = (tid & 31) << 2;
    const int rb = blockIdx.x * 32;
    const int r0 = rb + rg * 4;

    float4 acc0 = {0,0,0,0}, acc1 = {0,0,0,0}, acc2 = {0,0,0,0}, acc3 = {0,0,0,0};

    for (int half = 0; half < 2; ++half) {
        const int k0 = half * 64;
        __syncthreads();
        {
            const float4* W4 = (const float4*)(W + (size_t)k0 * 128);
            float4* wl4 = (float4*)wl;
            #pragma unroll
            for (int i = 0; i < 8; ++i) wl4[tid + i * 256] = W4[tid + i * 256];
        }
        #pragma unroll
        for (int i = 0; i < 2; ++i) {
            int f = tid + i * 256;
            int row = f >> 4, cc = f & 15;
            float4 v = *(const float4*)(X + (size_t)(rb + row) * 128 + k0 + cc * 4);
            *(float4*)&xl[row * 68 + cc * 4] = v;
        }
        __syncthreads();

        for (int k4 = 0; k4 < 16; ++k4) {
            const float* wr = wl + k4 * 4 * 128 + c4;
            float4 w0 = *(const float4*)(wr);
            float4 w1 = *(const float4*)(wr + 128);
            float4 w2 = *(const float4*)(wr + 256);
            float4 w3 = *(const float4*)(wr + 384);
            float4 xv0 = *(const float4*)&xl[(rg * 4 + 0) * 68 + k4 * 4];
            float4 xv1 = *(const float4*)&xl[(rg * 4 + 1) * 68 + k4 * 4];
            float4 xv2 = *(const float4*)&xl[(rg * 4 + 2) * 68 + k4 * 4];
            float4 xv3 = *(const float4*)&xl[(rg * 4 + 3) * 68 + k4 * 4];
            FMA4(acc0, xv0.x, w0) FMA4(acc0, xv0.y, w1) FMA4(acc0, xv0.z, w2) FMA4(acc0, xv0.w, w3)
            FMA4(acc1, xv1.x, w0) FMA4(acc1, xv1.y, w1) FMA4(acc1, xv1.z, w2) FMA4(acc1, xv1.w, w3)
            FMA4(acc2, xv2.x, w0) FMA4(acc2, xv2.y, w1) FMA4(acc2, xv2.z, w2) FMA4(acc2, xv2.w, w3)
            FMA4(acc3, xv3.x, w0) FMA4(acc3, xv3.y, w1) FMA4(acc3, xv3.z, w2) FMA4(acc3, xv3.w, w3)
        }
    }
    float d0 = dinv[r0], d1 = dinv[r0 + 1], d2 = dinv[r0 + 2], d3 = dinv[r0 + 3];
    uint2 o;
    // row stride in Hs is 128 bf16 = 64 dwords; c4 is element offset (c4/2 dwords)
    o.x = pack_bf16x2(acc0.x * d0, acc0.y * d0);
    o.y = pack_bf16x2(acc0.z * d0, acc0.w * d0);
    *(uint2*)(Hs + (size_t)(r0 + 0) * 64 + (c4 >> 1)) = o;
    o.x = pack_bf16x2(acc1.x * d1, acc1.y * d1);
    o.y = pack_bf16x2(acc1.z * d1, acc1.w * d1);
    *(uint2*)(Hs + (size_t)(r0 + 1) * 64 + (c4 >> 1)) = o;
    o.x = pack_bf16x2(acc2.x * d2, acc2.y * d2);
    o.y = pack_bf16x2(acc2.z * d2, acc2.w * d2);
    *(uint2*)(Hs + (size_t)(r0 + 2) * 64 + (c4 >> 1)) = o;
    o.x = pack_bf16x2(acc3.x * d3, acc3.y * d3);
    o.y = pack_bf16x2(acc3.z * d3, acc3.w * d3);
    *(uint2*)(Hs + (size_t)(r0 + 3) * 64 + (c4 >> 1)) = o;
}

// -------------------- SpMM on prescaled bf16 Hs: one wave per row, 2ch/lane.
// out[r] = relu( s * ( dinv[r]*(sum_edges Hs[c] + Hs[r]) ) + t )
__global__ __launch_bounds__(256) void spmm_bn_relu3(
    const uint* __restrict__ Hs, const int* __restrict__ cols,
    const int* __restrict__ rowptr, const float* __restrict__ dinv,
    const float* __restrict__ s, const float* __restrict__ t,
    float* __restrict__ Y) {
    const int lane = threadIdx.x & 63;
    const int r = blockIdx.x * 4 + (threadIdx.x >> 6);

    uint vself = Hs[(size_t)r * 64 + lane];
    float accx = __builtin_bit_cast(float, vself << 16);
    float accy = __builtin_bit_cast(float, vself & 0xffff0000u);
    const float di = dinv[r];
    const int e0 = rowptr[r], e1 = rowptr[r + 1];
    int j = e0;
    const int nfull = e0 + ((e1 - e0) & ~3);
    for (; j < nfull; j += 4) {
        int c0 = cols[j], c1 = cols[j + 1], c2 = cols[j + 2], c3 = cols[j + 3];
        uint v0 = Hs[(size_t)c0 * 64 + lane];
        uint v1 = Hs[(size_t)c1 * 64 + lane];
        uint v2 = Hs[(size_t)c2 * 64 + lane];
        uint v3 = Hs[(size_t)c3 * 64 + lane];
        accx += __builtin_bit_cast(float, v0 << 16);
        accy += __builtin_bit_cast(float, v0 & 0xffff0000u);
        accx += __builtin_bit_cast(float, v1 << 16);
        accy += __builtin_bit_cast(float, v1 & 0xffff0000u);
        accx += __builtin_bit_cast(float, v2 << 16);
        accy += __builtin_bit_cast(float, v2 & 0xffff0000u);
        accx += __builtin_bit_cast(float, v3 << 16);
        accy += __builtin_bit_cast(float, v3 & 0xffff0000u);
    }
    for (; j < e1; ++j) {
        uint v0 = Hs[(size_t)cols[j] * 64 + lane];
        accx += __builtin_bit_cast(float, v0 << 16);
        accy += __builtin_bit_cast(float, v0 & 0xffff0000u);
    }
    float2 sf = ((const float2*)s)[lane];
    float2 tf = ((const float2*)t)[lane];
    float2 o;
    o.x = fmaxf(fmaf(accx * di, sf.x, tf.x), 0.0f);
    o.y = fmaxf(fmaf(accy * di, sf.y, tf.y), 0.0f);
    ((float2*)Y)[(size_t)r * 64 + lane] = o;
}

// -------------------- final FC: out = [x0|x1|x2] @ fcW + fcb  (384 -> 40)
// 256 threads, 128 rows/block, grid=782. Thread owns 1 row x 20 cols.
// LDS: xs 128x16 stride 20 (10240 B) + wt 40x16 (2560 B).
__global__ __launch_bounds__(256) void final_gemm3(
    const float* __restrict__ X0, const float* __restrict__ X1,
    const float* __restrict__ X2, const float* __restrict__ fcW,
    const float* __restrict__ fcb, float* __restrict__ out) {
    __shared__ float xs[128 * 20];
    __shared__ float wt[40 * 16];    // wt[c][kk]

    const int t = threadIdx.x;
    const int row = t & 127;
    const int h = t >> 7;            // col half: cols h*20 .. h*20+19
    const int rbase = blockIdx.x * 128;
    const int r = rbase + row;

    float acc[20];
    #pragma unroll
    for (int c = 0; c < 20; ++c) acc[c] = 0.0f;

    const float* segs[3] = {X0, X1, X2};

    for (int ch = 0; ch < 24; ++ch) {
        const int k0 = ch * 16;
        const float* xseg = segs[k0 >> 7];
        const int koff = k0 & 127;
        __syncthreads();
        // stage X: 128 rows x 16 cols = 512 float4, 2 per thread (coalesced by 4)
        #pragma unroll
        for (int i = 0; i < 2; ++i) {
            int f = t + i * 256;
            int rw = f >> 2, cc = f & 3;
            int rr = rbase + rw;
            float4 v = {0, 0, 0, 0};
            if (rr < N_NODES)
                v = *(const float4*)(xseg + (size_t)rr * 128 + koff + cc * 4);
            *(float4*)&xs[rw * 20 + cc * 4] = v;
        }
        // stage W^T chunk: 640 floats
        #pragma unroll
        for (int i = 0; i < 3; ++i) {
            int idx = t + i * 256;
            if (idx < 640) {
                int c = idx % 40, kk = idx / 40;
                wt[c * 16 + kk] = fcW[(size_t)(k0 + kk) * 40 + c];
            }
        }
        __syncthreads();

        #pragma unroll
        for (int kk4 = 0; kk4 < 4; ++kk4) {
            float4 xv = *(const float4*)&xs[row * 20 + kk4 * 4];
            #pragma unroll
            for (int c = 0; c < 20; ++c) {
                float4 wv = *(const float4*)&wt[(h * 20 + c) * 16 + kk4 * 4];
                acc[c] = fmaf(xv.x, wv.x, acc[c]);
                acc[c] = fmaf(xv.y, wv.y, acc[c]);
                acc[c] = fmaf(xv.z, wv.z, acc[c]);
                acc[c] = fmaf(xv.w, wv.w, acc[c]);
            }
        }
    }

    if (r < N_NODES) {
        #pragma unroll
        for (int c4 = 0; c4 < 5; ++c4) {
            float4 o;
            o.x = acc[c4 * 4 + 0] + fcb[h * 20 + c4 * 4 + 0];
            o.y = acc[c4 * 4 + 1] + fcb[h * 20 + c4 * 4 + 1];
            o.z = acc[c4 * 4 + 2] + fcb[h * 20 + c4 * 4 + 2];
            o.w = acc[c4 * 4 + 3] + fcb[h * 20 + c4 * 4 + 3];
            *(float4*)(out + (size_t)r * 40 + h * 20 + c4 * 4) = o;
        }
    }
}

// ---------------------------------------------------------------------------
extern "C" void kernel_launch(void* const* d_in, const int* in_sizes, int n_in,
                              void* d_out, int out_size, void* d_ws, size_t ws_size,
                              hipStream_t stream) {
    const float* x   = (const float*)d_in[0];
    const int*   ei  = (const int*)d_in[1];
    const int* e_row = ei;
    const int* e_col = ei + N_EDGES;
    const float* W1  = (const float*)d_in[2];
    const float* b1  = (const float*)d_in[3];
    const float* W2  = (const float*)d_in[4];
    const float* b2  = (const float*)d_in[5];
    const float* g1  = (const float*)d_in[6];
    const float* be1 = (const float*)d_in[7];
    const float* m1  = (const float*)d_in[8];
    const float* v1  = (const float*)d_in[9];
    const float* g2  = (const float*)d_in[10];
    const float* be2 = (const float*)d_in[11];
    const float* m2  = (const float*)d_in[12];
    const float* v2  = (const float*)d_in[13];
    const float* fcW = (const float*)d_in[14];
    const float* fcb = (const float*)d_in[15];
    float* out = (float*)d_out;

    char* ws = (char*)d_ws;
    size_t off = 0;
    auto alloc = [&](size_t b) {
        char* p = ws + off;
        off += (b + 255) & ~(size_t)255;
        return p;
    };
    uint*  h      = (uint*)alloc((size_t)N_NODES * C_H * 2);   // bf16 Hs
    float* x1     = (float*)alloc((size_t)N_NODES * C_H * 4);
    float* x2     = (float*)alloc((size_t)N_NODES * C_H * 4);
    int*   deg    = (int*)alloc(N_NODES * 4);
    float* dinv   = (float*)alloc(N_NODES * 4);
    int*   rowptr = (int*)alloc((N_NODES + 1) * 4);
    int*   fillc  = (int*)alloc(N_NODES * 4);
    int*   cols   = (int*)alloc((size_t)N_EDGES * 4);
    int*   bsums  = (int*)alloc(128 * 4);
    float* coef   = (float*)alloc(512 * 4);
    float* s1 = coef, *t1 = coef + 128, *s2 = coef + 256, *t2 = coef + 384;

    const int nb_scan = (N_NODES + 1023) / 1024;

    zero_i32<<<(N_NODES + 255) / 256, 256, 0, stream>>>(deg, N_NODES);
    count_deg<<<(N_EDGES + 255) / 256, 256, 0, stream>>>(e_row, deg);
    compute_dinv<<<(N_NODES + 255) / 256, 256, 0, stream>>>(deg, dinv);
    scan_block<<<nb_scan, 1024, 0, stream>>>(deg, rowptr, bsums);
    scan_sums<<<1, 128, 0, stream>>>(bsums, nb_scan);
    add_offsets<<<nb_scan, 1024, 0, stream>>>(rowptr, bsums, fillc);
    fill_csr<<<(N_EDGES + 255) / 256, 256, 0, stream>>>(e_row, e_col, fillc, cols);
    bn_coef<<<1, 128, 0, stream>>>(b1, g1, be1, m1, v1, b2, g2, be2, m2, v2,
                                   s1, t1, s2, t2);

    gemm_scaled<<<N_NODES / 32, 256, 0, stream>>>(x, W1, dinv, h);
    spmm_bn_relu3<<<N_NODES / 4, 256, 0, stream>>>(h, cols, rowptr, dinv, s1, t1, x1);
    gemm_scaled<<<N_NODES / 32, 256, 0, stream>>>(x1, W2, dinv, h);
    spmm_bn_relu3<<<N_NODES / 4, 256, 0, stream>>>(h, cols, rowptr, dinv, s2, t2, x2);
    final_gemm3<<<(N_NODES + 127) / 128, 256, 0, stream>>>(x, x1, x2, fcW, fcb, out);
}